// Round 6
// baseline (1153.563 us; speedup 1.0000x reference)
//
#include <hip/hip_runtime.h>
#include <hip/hip_cooperative_groups.h>
#include <stdint.h>

namespace cg = cooperative_groups;

#define HNUM 240
#define WNUM 1216
#define BNUM 4
#define HWN (HNUM * WNUM)
#define NPIX (BNUM * HWN)
#define WP (WNUM + 3)
#define HP (HNUM + 3)
#define PLANE (HP * WP)
#define PP ((PLANE + 15) & ~15)      /* even per-batch pitch */
#define NPP (BNUM * PP)
#define PXT 8
#define NTHR (NPIX / PXT)            /* 145920 */
#define NBLK (NTHR / 256)            /* 570 */
#define NBORD 4385                   /* border+pad entries per batch */

union HCV { uint32_t u; _Float16 h[2]; };

__device__ __forceinline__ float fast_tanh(float x) {
    float ax = fabsf(x);
    float e  = __builtin_amdgcn_exp2f(ax * 2.885390081777927f);  // 2*log2(e)
    float t  = 1.0f - 2.0f * __builtin_amdgcn_rcpf(e + 1.0f);
    return copysignf(t, x);
}

__device__ __forceinline__ float h2lo(uint32_t u) { HCV c; c.u = u; return (float)c.h[0]; }
__device__ __forceinline__ float h2hi(uint32_t u) { HCV c; c.u = u; return (float)c.h[1]; }

// dual-plane bilinear tap: pEv = dword view of natural plane, pOd = +1-shifted.
__device__ __forceinline__ void tap_dual(uint32_t m, float a,
                                         const uint32_t* __restrict__ pEv,
                                         const uint32_t* __restrict__ pOd,
                                         int afp, float& acc) {
    int   rel = (int)(int16_t)(m & 0xffffu);
    float wy  = (float)((m >> 16) & 0xffu) * (1.0f / 255.0f);
    float wx  = (float)(m >> 24)           * (1.0f / 255.0f);
    int a0 = afp + rel;
    int a1 = a0 + WP;
    const uint32_t* r0 = (a0 & 1) ? pOd : pEv;
    const uint32_t* r1 = (a0 & 1) ? pEv : pOd;
    HCV c0, c1;
    c0.u = r0[a0 >> 1];   // (g00, g01)
    c1.u = r1[a1 >> 1];   // (g10, g11)
    float g00 = (float)c0.h[0], g01 = (float)c0.h[1];
    float g10 = (float)c1.h[0], g11 = (float)c1.h[1];
    float top = fmaf(wx, g01 - g00, g00);
    float bot = fmaf(wx, g11 - g10, g10);
    acc = fmaf(a, fmaf(wy, bot - top, top), acc);
}

__device__ __forceinline__ uint32_t build_tap(int h, int w, int dy, int dx,
                                              float offy, float offx, float& a) {
    float ys  = (float)(h + dy) + offy;
    float xs  = (float)(w + dx) + offx;
    float y0f = floorf(ys), x0f = floorf(xs);
    int   y0  = (int)y0f,  x0  = (int)x0f;
    float wy  = ys - y0f,  wx  = xs - x0f;
    uint32_t qy = (uint32_t)(wy * 255.0f + 0.5f); if (qy > 255) qy = 255;
    uint32_t qx = (uint32_t)(wx * 255.0f + 0.5f); if (qx > 255) qx = 255;
    bool valid = (y0 >= -1) & (y0 <= HNUM) & (x0 >= -1) & (x0 <= WNUM);
    int rel = (y0 - h) * WP + (x0 - w);
    if (!valid || rel < -32768 || rel > 32767) { rel = 0; qy = 0; qx = 0; a = 0.f; }
    return (uint32_t)(uint16_t)(int16_t)rel | (qy << 16) | (qx << 24);
}

// ---------------------------------------------------------------------------
// persistent fused kernel: meta in registers, 6 steps with grid.sync()
// thread tid: lane l = tid&63, wave wv = tid>>6; wave owns px [wv*512, wv*512+512)
// lane's px j = wv*512 + j*64 + l  (coalesced stores/loads per j)
// ---------------------------------------------------------------------------
__global__ __launch_bounds__(256, 3) void nlspn_fused(
    const float* __restrict__ aff_raw,
    const float* __restrict__ offset,
    const float* __restrict__ conf,
    const float* __restrict__ pred,
    const float* __restrict__ dep,
    const float* __restrict__ scale,
    _Float16* __restrict__ A0, _Float16* __restrict__ A1,
    _Float16* __restrict__ B0, _Float16* __restrict__ B1,
    float* __restrict__ out)
{
    cg::grid_group grid = cg::this_grid();

    int tid = blockIdx.x * 256 + (int)threadIdx.x;     // < NTHR exactly
    int l   = tid & 63;
    int wv  = tid >> 6;
    int pxb = wv * 512 + l;                            // lane's first px
    int b   = pxb / HWN;                               // uniform per wave
    int hwb = pxb - b * HWN;

    // ---- zero plane borders + pads (disjoint from interiors; no pre-sync) ----
    if (tid < BNUM * NBORD) {
        int bb  = tid / NBORD;
        int idx = tid - bb * NBORD;
        int cell;
        if (idx < 3 * WP) {
            int r3 = idx / WP;
            int c  = idx - r3 * WP;
            int ph = (r3 == 0) ? 0 : (240 + r3);       // rows 0, 241, 242
            cell = ph * WP + c;
        } else if (idx < 3 * WP + 720) {
            int i2 = idx - 3 * WP;
            int r  = i2 / 3;
            int c3 = i2 - r * 3;
            int c  = (c3 == 0) ? 0 : (WNUM + c3);      // cols 0, 1217, 1218
            cell = (1 + r) * WP + c;
        } else {
            cell = PLANE + (idx - (3 * WP + 720));     // pads PLANE..PP
        }
        size_t base = (size_t)bb * PP;
        if (cell < PP) {
            A0[base + cell] = (_Float16)0.f;
            B0[base + cell] = (_Float16)0.f;
        }
        if (cell >= 1) {
            A1[base + cell - 1] = (_Float16)0.f;
            B1[base + cell - 1] = (_Float16)0.f;
        }
    }

    // ---- build meta into registers + write ff0 ----
    float s    = scale[0];
    float invs = 1.0f / (s + 1e-8f);

    uint32_t taps[PXT][8];
    uint32_t affH[PXT][4];
    uint32_t auxc[PXT];      // half2(aref, conf)
    float    depv[PXT];
    int      bpv[PXT];

    const float* arb = aff_raw + (size_t)b * 8 * HWN;
    const float* ofb = offset  + (size_t)b * 16 * HWN;

#pragma unroll
    for (int j = 0; j < PXT; ++j) {
        int hw = hwb + 64 * j;
        int h  = hw / WNUM;
        int w  = hw - h * WNUM;
        int bp = (h + 1) * WP + (w + 1);
        bpv[j] = bp;

        float aa[8];
        float asum = 0.f;
#pragma unroll
        for (int k = 0; k < 8; ++k) {
            float t = fast_tanh(arb[(size_t)k * HWN + hw]) * invs;
            aa[k] = t;
            asum += fabsf(t);
        }
        float rden = 1.0f / fmaxf(asum + 1e-4f, 1.0f);
        float sm = 0.f;
#pragma unroll
        for (int k = 0; k < 8; ++k) { aa[k] *= rden; sm += aa[k]; }
        float aref = 1.0f - sm;

#pragma unroll
        for (int k = 0; k < 8; ++k) {
            int k9 = (k < 4) ? k : k + 1;
            int dy = k9 / 3 - 1;
            int dx = k9 - (k9 / 3) * 3 - 1;
            float offy = ofb[(size_t)(2 * k)     * HWN + hw];
            float offx = ofb[(size_t)(2 * k + 1) * HWN + hw];
            taps[j][k] = build_tap(h, w, dy, dx, offy, offx, aa[k]);
        }

        HCV cv;
#pragma unroll
        for (int q = 0; q < 4; ++q) {
            cv.h[0] = (_Float16)aa[2 * q];
            cv.h[1] = (_Float16)aa[2 * q + 1];
            affH[j][q] = cv.u;
        }

        int   gp = pxb + 64 * j;
        float cf = conf[gp];
        float dd = dep[gp];
        float pp = pred[gp];
        cv.h[0] = (_Float16)aref;
        cv.h[1] = (_Float16)cf;
        auxc[j] = cv.u;
        depv[j] = dd;

        _Float16 o = (_Float16)(pp * cf);
        size_t gb = (size_t)b * PP + bp;
        A0[gb]     = o;
        A1[gb - 1] = o;
    }

    grid.sync();

    // ---- 6 propagation steps ----
    _Float16 *I0 = A0, *I1 = A1, *O0 = B0, *O1 = B1;
#pragma unroll 1
    for (int st = 0; st < 6; ++st) {
        const _Float16* I0b = I0 + (size_t)b * PP;
        const uint32_t* pEv = (const uint32_t*)I0b;
        const uint32_t* pOd = (const uint32_t*)(I1 + (size_t)b * PP);
        _Float16* O0b = O0 + (size_t)b * PP;
        _Float16* O1b = O1 + (size_t)b * PP;

#pragma unroll
        for (int j = 0; j < PXT; ++j) {
            int bp = bpv[j];
            float aref = h2lo(auxc[j]);
            float cf   = h2hi(auxc[j]);
            float acc  = aref * (float)I0b[bp];
#pragma unroll
            for (int k = 0; k < 8; ++k) {
                float a = (k & 1) ? h2hi(affH[j][k >> 1]) : h2lo(affH[j][k >> 1]);
                tap_dual(taps[j][k], a, pEv, pOd, bp, acc);
            }
            float dd   = depv[j];
            float feat = (dd > 0.f) ? dd : acc;
            if (st == 5) {
                out[pxb + 64 * j] = feat;
            } else {
                _Float16 o = (_Float16)(feat * cf);
                O0b[bp]     = o;
                O1b[bp - 1] = o;
            }
        }

        if (st < 5) grid.sync();
        _Float16* t;
        t = I0; I0 = O0; O0 = t;
        t = I1; I1 = O1; O1 = t;
    }
}

// ---------------------------------------------------------------------------
// fallback (round-1 style) if cooperative launch unavailable
// ---------------------------------------------------------------------------
__global__ __launch_bounds__(256) void nlspn_init_kernel(
    const float* __restrict__ pred,
    const float* __restrict__ conf,
    float* __restrict__ ff)
{
    int p = blockIdx.x * blockDim.x + threadIdx.x;
    if (p < NPIX) ff[p] = pred[p] * conf[p];
}

template <bool LAST>
__global__ __launch_bounds__(256) void nlspn_prop_kernel(
    const float* __restrict__ aff_raw,
    const float* __restrict__ offset,
    const float* __restrict__ conf,
    const float* __restrict__ dep,
    const float* __restrict__ scale,
    const float* __restrict__ ff_in,
    float* __restrict__ out)
{
    int p = blockIdx.x * blockDim.x + threadIdx.x;
    if (p >= NPIX) return;
    int b  = p / HWN;
    int hw = p - b * HWN;
    int h  = hw / WNUM;
    int w  = hw - h * WNUM;

    float s    = scale[0];
    float invs = 1.0f / (s + 1e-8f);

    float a[8];
    const float* ar = aff_raw + (size_t)b * 8 * HWN + hw;
#pragma unroll
    for (int k = 0; k < 8; ++k) a[k] = ar[(size_t)k * HWN];

    float asum = 0.0f;
#pragma unroll
    for (int k = 0; k < 8; ++k) {
        a[k] = fast_tanh(a[k]) * invs;
        asum += fabsf(a[k]);
    }
    asum += 1e-4f;
    float rden = 1.0f / fmaxf(asum, 1.0f);
    float suma = 0.0f;
#pragma unroll
    for (int k = 0; k < 8; ++k) { a[k] *= rden; suma += a[k]; }
    float aref = 1.0f - suma;

    const float* ffb = ff_in + (size_t)b * HWN;
    float acc = aref * ffb[hw];

    const float* off = offset + (size_t)b * 16 * HWN + hw;
#pragma unroll
    for (int k = 0; k < 8; ++k) {
        int   k9 = (k < 4) ? k : k + 1;
        int   dy = k9 / 3 - 1;
        int   dx = k9 - (k9 / 3) * 3 - 1;
        float offy = off[(size_t)(2 * k)     * HWN];
        float offx = off[(size_t)(2 * k + 1) * HWN];
        float ysf = (float)(h + dy) + offy;
        float xsf = (float)(w + dx) + offx;
        float y0f = floorf(ysf);
        float x0f = floorf(xsf);
        float wy  = ysf - y0f;
        float wx  = xsf - x0f;
        int   y0  = (int)y0f;
        int   x0  = (int)x0f;
        bool yv0 = (y0 >= 0)  & (y0 < HNUM);
        bool yv1 = (y0 >= -1) & (y0 + 1 < HNUM);
        bool xv0 = (x0 >= 0)  & (x0 < WNUM);
        bool xv1 = (x0 >= -1) & (x0 + 1 < WNUM);
        int row0 = y0 * WNUM;
        float g00 = 0.f, g01 = 0.f, g10 = 0.f, g11 = 0.f;
        if (yv0 & xv0) g00 = ffb[row0 + x0];
        if (yv0 & xv1) g01 = ffb[row0 + x0 + 1];
        if (yv1 & xv0) g10 = ffb[row0 + WNUM + x0];
        if (yv1 & xv1) g11 = ffb[row0 + WNUM + x0 + 1];
        float sampled = (1.f - wy) * ((1.f - wx) * g00 + wx * g01)
                      +        wy  * ((1.f - wx) * g10 + wx * g11);
        acc += a[k] * sampled;
    }

    float dd   = dep[p];
    float feat = (dd > 0.0f) ? dd : acc;
    if (LAST) out[p] = feat;
    else      out[p] = feat * conf[p];
}

// ---------------------------------------------------------------------------
extern "C" void kernel_launch(void* const* d_in, const int* in_sizes, int n_in,
                              void* d_out, int out_size, void* d_ws, size_t ws_size,
                              hipStream_t stream)
{
    const float* aff_raw = (const float*)d_in[0];
    const float* offset  = (const float*)d_in[1];
    const float* conf    = (const float*)d_in[2];
    const float* pred    = (const float*)d_in[3];
    const float* dep     = (const float*)d_in[4];
    const float* scale   = (const float*)d_in[5];
    float* out = (float*)d_out;

    const size_t planeBytes = (size_t)NPP * 2;
    bool launched = false;

    if (ws_size >= 4 * planeBytes + 64) {
        char* wb = (char*)d_ws;
        _Float16* A0 = (_Float16*)wb;  wb += planeBytes;
        _Float16* A1 = (_Float16*)wb;  wb += planeBytes;
        _Float16* B0 = (_Float16*)wb;  wb += planeBytes;
        _Float16* B1 = (_Float16*)wb;

        void* args[] = {
            (void*)&aff_raw, (void*)&offset, (void*)&conf, (void*)&pred,
            (void*)&dep, (void*)&scale,
            (void*)&A0, (void*)&A1, (void*)&B0, (void*)&B1, (void*)&out
        };
        hipError_t err = hipLaunchCooperativeKernel(
            (const void*)nlspn_fused, dim3(NBLK), dim3(256), args, 0, stream);
        if (err == hipSuccess) {
            launched = true;
        } else {
            (void)hipGetLastError();   // clear sticky error, take fallback
        }
    }

    if (!launched) {
        const int threads = 256;
        const int blocksP = (NPIX + threads - 1) / threads;
        float* ws = (float*)d_ws;
        nlspn_init_kernel<<<blocksP, threads, 0, stream>>>(pred, conf, out);
        nlspn_prop_kernel<false><<<blocksP, threads, 0, stream>>>(aff_raw, offset, conf, dep, scale, out, ws);
        nlspn_prop_kernel<false><<<blocksP, threads, 0, stream>>>(aff_raw, offset, conf, dep, scale, ws, out);
        nlspn_prop_kernel<false><<<blocksP, threads, 0, stream>>>(aff_raw, offset, conf, dep, scale, out, ws);
        nlspn_prop_kernel<false><<<blocksP, threads, 0, stream>>>(aff_raw, offset, conf, dep, scale, ws, out);
        nlspn_prop_kernel<false><<<blocksP, threads, 0, stream>>>(aff_raw, offset, conf, dep, scale, out, ws);
        nlspn_prop_kernel<true ><<<blocksP, threads, 0, stream>>>(aff_raw, offset, conf, dep, scale, ws, out);
    }
}

// Round 7
// 993.744 us; speedup vs baseline: 1.1608x; 1.1608x over previous
//
#include <hip/hip_runtime.h>
#include <hip/hip_cooperative_groups.h>
#include <stdint.h>

namespace cg = cooperative_groups;

#define HNUM 240
#define WNUM 1216
#define BNUM 4
#define HWN (HNUM * WNUM)
#define NPIX (BNUM * HWN)
#define WP (WNUM + 3)
#define HP (HNUM + 3)
#define PLANE (HP * WP)
#define PP ((PLANE + 15) & ~15)      /* even per-batch pitch (296224) */
#define NPP (BNUM * PP)
#define PXT 10
#define NTHR (NPIX / PXT)            /* 116736 */
#define NBLK (NTHR / 256)            /* 456 = 8 * 57 */
#define XCHUNK (NBLK / 8)            /* 57 */
#define WAVEPX (64 * PXT)            /* 640; HWN/640 = 456 exact */
#define NBORD (3 * WP + 3 * HNUM + (PP - PLANE))   /* 4384 */

union HCV { uint32_t u; _Float16 h[2]; };

__device__ __forceinline__ float fast_tanh(float x) {
    float ax = fabsf(x);
    float e  = __builtin_amdgcn_exp2f(ax * 2.885390081777927f);  // 2*log2(e)
    float t  = 1.0f - 2.0f * __builtin_amdgcn_rcpf(e + 1.0f);
    return copysignf(t, x);
}

__device__ __forceinline__ float h2lo(uint32_t u) { HCV c; c.u = u; return (float)c.h[0]; }
__device__ __forceinline__ float h2hi(uint32_t u) { HCV c; c.u = u; return (float)c.h[1]; }

// dual-plane bilinear tap: pEv = dword view of natural plane, pOd = +1-shifted.
__device__ __forceinline__ void tap_dual(uint32_t m, float a,
                                         const uint32_t* __restrict__ pEv,
                                         const uint32_t* __restrict__ pOd,
                                         int afp, float& acc) {
    int   rel = (int)(int16_t)(m & 0xffffu);
    float wy  = (float)((m >> 16) & 0xffu) * (1.0f / 255.0f);
    float wx  = (float)(m >> 24)           * (1.0f / 255.0f);
    int a0 = afp + rel;
    int a1 = a0 + WP;
    const uint32_t* r0 = (a0 & 1) ? pOd : pEv;
    const uint32_t* r1 = (a0 & 1) ? pEv : pOd;
    HCV c0, c1;
    c0.u = r0[a0 >> 1];   // (g00, g01)
    c1.u = r1[a1 >> 1];   // (g10, g11)
    float g00 = (float)c0.h[0], g01 = (float)c0.h[1];
    float g10 = (float)c1.h[0], g11 = (float)c1.h[1];
    float top = fmaf(wx, g01 - g00, g00);
    float bot = fmaf(wx, g11 - g10, g10);
    acc = fmaf(a, fmaf(wy, bot - top, top), acc);
}

__device__ __forceinline__ uint32_t build_tap(int h, int w, int dy, int dx,
                                              float offy, float offx, float& a) {
    float ys  = (float)(h + dy) + offy;
    float xs  = (float)(w + dx) + offx;
    float y0f = floorf(ys), x0f = floorf(xs);
    int   y0  = (int)y0f,  x0  = (int)x0f;
    float wy  = ys - y0f,  wx  = xs - x0f;
    uint32_t qy = (uint32_t)(wy * 255.0f + 0.5f); if (qy > 255) qy = 255;
    uint32_t qx = (uint32_t)(wx * 255.0f + 0.5f); if (qx > 255) qx = 255;
    bool valid = (y0 >= -1) & (y0 <= HNUM) & (x0 >= -1) & (x0 <= WNUM);
    int rel = (y0 - h) * WP + (x0 - w);
    if (!valid || rel < -32768 || rel > 32767) { rel = 0; qy = 0; qx = 0; a = 0.f; }
    return (uint32_t)(uint16_t)(int16_t)rel | (qy << 16) | (qx << 24);
}

// ---------------------------------------------------------------------------
// persistent fused kernel: meta in registers, 6 steps with grid.sync().
// 456 blocks x 256 thr, 10 px/thread. Wave wv owns px [wv*640, wv*640+640),
// lane l handles px wv*640 + j*64 + l (coalesced). Batch uniform per wave.
// Block index XCD-chunked so each XCD's gathers stay in its L2.
// ---------------------------------------------------------------------------
__global__ __launch_bounds__(256, 2) void nlspn_fused(
    const float* __restrict__ aff_raw,
    const float* __restrict__ offset,
    const float* __restrict__ conf,
    const float* __restrict__ pred,
    const float* __restrict__ dep,
    const float* __restrict__ scale,
    _Float16* __restrict__ A0, _Float16* __restrict__ A1,
    _Float16* __restrict__ B0, _Float16* __restrict__ B1,
    float* __restrict__ out)
{
    cg::grid_group grid = cg::this_grid();

    int bid = blockIdx.x;
    int nb  = (bid & 7) * XCHUNK + (bid >> 3);         // bijective: 456 = 8*57
    int tid = nb * 256 + (int)threadIdx.x;             // < NTHR exactly
    int l   = tid & 63;
    int wv  = tid >> 6;
    int pxb = wv * WAVEPX + l;                         // lane's first px
    int b   = pxb / HWN;                               // uniform per wave
    int hwb = pxb - b * HWN;

    // ---- zero plane borders + pads (disjoint from interiors) ----
    if (tid < BNUM * NBORD) {
        int bb  = tid / NBORD;
        int idx = tid - bb * NBORD;
        int cell;
        if (idx < 3 * WP) {
            int r3 = idx / WP;
            int c  = idx - r3 * WP;
            int ph = (r3 == 0) ? 0 : (240 + r3);       // rows 0, 241, 242
            cell = ph * WP + c;
        } else if (idx < 3 * WP + 3 * HNUM) {
            int i2 = idx - 3 * WP;
            int r  = i2 / 3;
            int c3 = i2 - r * 3;
            int c  = (c3 == 0) ? 0 : (WNUM + c3);      // cols 0, 1217, 1218
            cell = (1 + r) * WP + c;
        } else {
            cell = PLANE + (idx - (3 * WP + 3 * HNUM));   // pads PLANE..PP
        }
        size_t base = (size_t)bb * PP;
        if (cell < PP) {
            A0[base + cell] = (_Float16)0.f;
            B0[base + cell] = (_Float16)0.f;
        }
        if (cell >= 1) {
            A1[base + cell - 1] = (_Float16)0.f;
            B1[base + cell - 1] = (_Float16)0.f;
        }
    }

    // ---- build meta into registers + write ff0 ----
    float s    = scale[0];
    float invs = 1.0f / (s + 1e-8f);

    uint32_t taps[PXT][8];   // 80 VGPR
    uint32_t affH[PXT][4];   // 40 VGPR
    uint32_t auxc[PXT];      // half2(aref, conf)   10 VGPR
    float    depv[PXT];      // 10 VGPR
    int      bpv[PXT];       // 10 VGPR

    const float* arb = aff_raw + (size_t)b * 8 * HWN;
    const float* ofb = offset  + (size_t)b * 16 * HWN;

#pragma unroll
    for (int j = 0; j < PXT; ++j) {
        int hw = hwb + 64 * j;
        int h  = hw / WNUM;
        int w  = hw - h * WNUM;
        int bp = (h + 1) * WP + (w + 1);
        bpv[j] = bp;

        float aa[8];
        float asum = 0.f;
#pragma unroll
        for (int k = 0; k < 8; ++k) {
            float t = fast_tanh(arb[(size_t)k * HWN + hw]) * invs;
            aa[k] = t;
            asum += fabsf(t);
        }
        float rden = 1.0f / fmaxf(asum + 1e-4f, 1.0f);
        float sm = 0.f;
#pragma unroll
        for (int k = 0; k < 8; ++k) { aa[k] *= rden; sm += aa[k]; }
        float aref = 1.0f - sm;

#pragma unroll
        for (int k = 0; k < 8; ++k) {
            int k9 = (k < 4) ? k : k + 1;
            int dy = k9 / 3 - 1;
            int dx = k9 - (k9 / 3) * 3 - 1;
            float offy = ofb[(size_t)(2 * k)     * HWN + hw];
            float offx = ofb[(size_t)(2 * k + 1) * HWN + hw];
            taps[j][k] = build_tap(h, w, dy, dx, offy, offx, aa[k]);
        }

        HCV cv;
#pragma unroll
        for (int q = 0; q < 4; ++q) {
            cv.h[0] = (_Float16)aa[2 * q];
            cv.h[1] = (_Float16)aa[2 * q + 1];
            affH[j][q] = cv.u;
        }

        int   gp = pxb + 64 * j;
        float cf = conf[gp];
        float dd = dep[gp];
        float pp = pred[gp];
        cv.h[0] = (_Float16)aref;
        cv.h[1] = (_Float16)cf;
        auxc[j] = cv.u;
        depv[j] = dd;

        _Float16 o = (_Float16)(pp * cf);
        size_t gb = (size_t)b * PP + bp;
        A0[gb]     = o;
        A1[gb - 1] = o;
    }

    grid.sync();

    // ---- 6 propagation steps ----
    _Float16 *I0 = A0, *I1 = A1, *O0 = B0, *O1 = B1;
#pragma unroll 1
    for (int st = 0; st < 6; ++st) {
        const _Float16* I0b = I0 + (size_t)b * PP;
        const uint32_t* pEv = (const uint32_t*)I0b;
        const uint32_t* pOd = (const uint32_t*)(I1 + (size_t)b * PP);
        _Float16* O0b = O0 + (size_t)b * PP;
        _Float16* O1b = O1 + (size_t)b * PP;

#pragma unroll
        for (int j = 0; j < PXT; ++j) {
            int bp = bpv[j];
            float aref = h2lo(auxc[j]);
            float cf   = h2hi(auxc[j]);
            float acc  = aref * (float)I0b[bp];
#pragma unroll
            for (int k = 0; k < 8; ++k) {
                float a = (k & 1) ? h2hi(affH[j][k >> 1]) : h2lo(affH[j][k >> 1]);
                tap_dual(taps[j][k], a, pEv, pOd, bp, acc);
            }
            float dd   = depv[j];
            float feat = (dd > 0.f) ? dd : acc;
            if (st == 5) {
                out[pxb + 64 * j] = feat;
            } else {
                _Float16 o = (_Float16)(feat * cf);
                O0b[bp]     = o;
                O1b[bp - 1] = o;
            }
        }

        if (st < 5) grid.sync();
        _Float16* t;
        t = I0; I0 = O0; O0 = t;
        t = I1; I1 = O1; O1 = t;
    }
}

// ---------------------------------------------------------------------------
// fallback (round-1 style) if cooperative launch unavailable
// ---------------------------------------------------------------------------
__global__ __launch_bounds__(256) void nlspn_init_kernel(
    const float* __restrict__ pred,
    const float* __restrict__ conf,
    float* __restrict__ ff)
{
    int p = blockIdx.x * blockDim.x + threadIdx.x;
    if (p < NPIX) ff[p] = pred[p] * conf[p];
}

template <bool LAST>
__global__ __launch_bounds__(256) void nlspn_prop_kernel(
    const float* __restrict__ aff_raw,
    const float* __restrict__ offset,
    const float* __restrict__ conf,
    const float* __restrict__ dep,
    const float* __restrict__ scale,
    const float* __restrict__ ff_in,
    float* __restrict__ out)
{
    int p = blockIdx.x * blockDim.x + threadIdx.x;
    if (p >= NPIX) return;
    int b  = p / HWN;
    int hw = p - b * HWN;
    int h  = hw / WNUM;
    int w  = hw - h * WNUM;

    float s    = scale[0];
    float invs = 1.0f / (s + 1e-8f);

    float a[8];
    const float* ar = aff_raw + (size_t)b * 8 * HWN + hw;
#pragma unroll
    for (int k = 0; k < 8; ++k) a[k] = ar[(size_t)k * HWN];

    float asum = 0.0f;
#pragma unroll
    for (int k = 0; k < 8; ++k) {
        a[k] = fast_tanh(a[k]) * invs;
        asum += fabsf(a[k]);
    }
    asum += 1e-4f;
    float rden = 1.0f / fmaxf(asum, 1.0f);
    float suma = 0.0f;
#pragma unroll
    for (int k = 0; k < 8; ++k) { a[k] *= rden; suma += a[k]; }
    float aref = 1.0f - suma;

    const float* ffb = ff_in + (size_t)b * HWN;
    float acc = aref * ffb[hw];

    const float* off = offset + (size_t)b * 16 * HWN + hw;
#pragma unroll
    for (int k = 0; k < 8; ++k) {
        int   k9 = (k < 4) ? k : k + 1;
        int   dy = k9 / 3 - 1;
        int   dx = k9 - (k9 / 3) * 3 - 1;
        float offy = off[(size_t)(2 * k)     * HWN];
        float offx = off[(size_t)(2 * k + 1) * HWN];
        float ysf = (float)(h + dy) + offy;
        float xsf = (float)(w + dx) + offx;
        float y0f = floorf(ysf);
        float x0f = floorf(xsf);
        float wy  = ysf - y0f;
        float wx  = xsf - x0f;
        int   y0  = (int)y0f;
        int   x0  = (int)x0f;
        bool yv0 = (y0 >= 0)  & (y0 < HNUM);
        bool yv1 = (y0 >= -1) & (y0 + 1 < HNUM);
        bool xv0 = (x0 >= 0)  & (x0 < WNUM);
        bool xv1 = (x0 >= -1) & (x0 + 1 < WNUM);
        int row0 = y0 * WNUM;
        float g00 = 0.f, g01 = 0.f, g10 = 0.f, g11 = 0.f;
        if (yv0 & xv0) g00 = ffb[row0 + x0];
        if (yv0 & xv1) g01 = ffb[row0 + x0 + 1];
        if (yv1 & xv0) g10 = ffb[row0 + WNUM + x0];
        if (yv1 & xv1) g11 = ffb[row0 + WNUM + x0 + 1];
        float sampled = (1.f - wy) * ((1.f - wx) * g00 + wx * g01)
                      +        wy  * ((1.f - wx) * g10 + wx * g11);
        acc += a[k] * sampled;
    }

    float dd   = dep[p];
    float feat = (dd > 0.0f) ? dd : acc;
    if (LAST) out[p] = feat;
    else      out[p] = feat * conf[p];
}

// ---------------------------------------------------------------------------
extern "C" void kernel_launch(void* const* d_in, const int* in_sizes, int n_in,
                              void* d_out, int out_size, void* d_ws, size_t ws_size,
                              hipStream_t stream)
{
    const float* aff_raw = (const float*)d_in[0];
    const float* offset  = (const float*)d_in[1];
    const float* conf    = (const float*)d_in[2];
    const float* pred    = (const float*)d_in[3];
    const float* dep     = (const float*)d_in[4];
    const float* scale   = (const float*)d_in[5];
    float* out = (float*)d_out;

    const size_t planeBytes = (size_t)NPP * 2;
    bool launched = false;

    if (ws_size >= 4 * planeBytes + 64) {
        char* wb = (char*)d_ws;
        _Float16* A0 = (_Float16*)wb;  wb += planeBytes;
        _Float16* A1 = (_Float16*)wb;  wb += planeBytes;
        _Float16* B0 = (_Float16*)wb;  wb += planeBytes;
        _Float16* B1 = (_Float16*)wb;

        void* args[] = {
            (void*)&aff_raw, (void*)&offset, (void*)&conf, (void*)&pred,
            (void*)&dep, (void*)&scale,
            (void*)&A0, (void*)&A1, (void*)&B0, (void*)&B1, (void*)&out
        };
        hipError_t err = hipLaunchCooperativeKernel(
            (const void*)nlspn_fused, dim3(NBLK), dim3(256), args, 0, stream);
        if (err == hipSuccess) {
            launched = true;
        } else {
            (void)hipGetLastError();   // clear sticky error, take fallback
        }
    }

    if (!launched) {
        const int threads = 256;
        const int blocksP = (NPIX + threads - 1) / threads;
        float* ws = (float*)d_ws;
        nlspn_init_kernel<<<blocksP, threads, 0, stream>>>(pred, conf, out);
        nlspn_prop_kernel<false><<<blocksP, threads, 0, stream>>>(aff_raw, offset, conf, dep, scale, out, ws);
        nlspn_prop_kernel<false><<<blocksP, threads, 0, stream>>>(aff_raw, offset, conf, dep, scale, ws, out);
        nlspn_prop_kernel<false><<<blocksP, threads, 0, stream>>>(aff_raw, offset, conf, dep, scale, out, ws);
        nlspn_prop_kernel<false><<<blocksP, threads, 0, stream>>>(aff_raw, offset, conf, dep, scale, ws, out);
        nlspn_prop_kernel<false><<<blocksP, threads, 0, stream>>>(aff_raw, offset, conf, dep, scale, out, ws);
        nlspn_prop_kernel<true ><<<blocksP, threads, 0, stream>>>(aff_raw, offset, conf, dep, scale, ws, out);
    }
}